// Round 9
// baseline (578.334 us; speedup 1.0000x reference)
//
#include <hip/hip_runtime.h>
#include <math.h>

typedef unsigned short u16;
typedef unsigned int u32;
typedef __attribute__((ext_vector_type(8))) short s16x8;
typedef __attribute__((ext_vector_type(4))) unsigned short u16x4;
typedef __attribute__((ext_vector_type(4))) float f32x4;

__device__ __forceinline__ float bf2f(u16 x) { return __uint_as_float(((u32)x) << 16); }
__device__ __forceinline__ u16 f2bf(float f) {
    u32 u = __float_as_uint(f);
    u32 r = u + 0x7fffu + ((u >> 16) & 1u);   // RNE
    return (u16)(r >> 16);
}

// async global->LDS, 16 B per lane (LDS dest = wave-uniform base + lane*16).
__device__ __forceinline__ void gll16(const u16* g, u16* l) {
    __builtin_amdgcn_global_load_lds((const __attribute__((address_space(1))) void*)g,
                                     (__attribute__((address_space(3))) void*)l,
                                     16, 0, 0);
}

// ---------------------------------------------------------------------------
// GEMM v3b (r6, best-known): 128x128 tile, BK=64, 4 waves, 2 LDS buffers,
// counted vmcnt(8) depth-2, full fence protocol. See r6 notes.
// MODE 2/3/4/5 as before.
// ---------------------------------------------------------------------------
template <int MODE>
__global__ __launch_bounds__(256) void gemm128(
    const u16* __restrict__ Abf, const u16* __restrict__ A2b,
    const u16* __restrict__ BT, const float* __restrict__ bias,
    u16* __restrict__ Cb, float* __restrict__ Cf, u16* __restrict__ C2b,
    const float* __restrict__ auxemb, const int* __restrict__ auxidx,
    float* __restrict__ absum, int M, int N, int K)
{
    __shared__ u16 lsmem[2 * 16384];   // 2 x (A[128][64] | B[128][64]) = 64 KB

    const int tid = threadIdx.x;
    const int wave = tid >> 6;
    const int lane = tid & 63;
    const int l15 = lane & 15;
    const int quad = lane >> 4;
    const int wr = wave >> 1, wc = wave & 1;

    // XCD-bijective swizzle (m204): contiguous flat-id chunk per XCD.
    const int gx = gridDim.x;
    const int nwg = gx * gridDim.y;
    int flat = blockIdx.y * gx + blockIdx.x;
    {
        const int q = nwg >> 3, r8 = nwg & 7;
        const int xcd = flat & 7, loc = flat >> 3;
        flat = (xcd < r8 ? xcd * (q + 1) : r8 * (q + 1) + (xcd - r8) * q) + loc;
    }
    const int tileRow = (flat / gx) * 128;
    const int tileCol = (flat % gx) * 128;

    // staging map: instr j (0..3), thread t -> flat chunk j*256+t;
    // row = chunk>>3 (0..127), chunkpos = chunk&7 (8 x 16B = 128-B row, BK=64);
    // source chunk is XOR-swizzled by row&7 (linear LDS dest).
    const int srow = tid >> 3;             // + j*32
    const int ks = ((tid & 7) ^ (srow & 7)) * 8;   // u16 offset in [0,64)

    const u16 *gA[4], *gB[4], *gA2[4];
#pragma unroll
    for (int j = 0; j < 4; j++) {
        const int ra = j * 32 + srow;
        const int pa = (MODE == 3) ? 256 : K;
        gA[j] = Abf + (size_t)(tileRow + ra) * pa + ks;
        gB[j] = BT + (size_t)(tileCol + ra) * K + ks;
        if (MODE == 3)
            gA2[j] = A2b + (size_t)auxidx[min(tileRow + ra, M - 1)] * 256 + ks;
        else
            gA2[j] = nullptr;
    }

#define STAGE(TK, BUF)                                                         \
    {                                                                          \
        u16* lb_ = lsmem + (BUF)*16384;                                        \
        const int kk_ = (TK)*64;                                               \
        _Pragma("unroll")                                                      \
        for (int j = 0; j < 4; j++) {                                          \
            const u16* sa;                                                     \
            if (MODE == 3) sa = (kk_ < 256) ? gA[j] + kk_ : gA2[j] + (kk_ - 256); \
            else sa = gA[j] + kk_;                                             \
            gll16(sa, lb_ + j * 2048 + tid * 8);                               \
            gll16(gB[j] + kk_, lb_ + 8192 + j * 2048 + tid * 8);               \
        }                                                                      \
    }

    f32x4 acc[4][4] = {};
    const int nt = K >> 6;

    STAGE(0, 0);
    STAGE(1, 1);

    for (int t = 0; t < nt; ++t) {
        // each wave: own tile-t loads landed; barrier: ALL waves' landed.
        if (t + 2 < nt) asm volatile("s_waitcnt vmcnt(8)" ::: "memory");
        else            asm volatile("s_waitcnt vmcnt(0)" ::: "memory");
        __builtin_amdgcn_s_barrier();
        __builtin_amdgcn_sched_barrier(0);   // nothing hoists above barrier

        const u16* lb = lsmem + (t & 1) * 16384;
#pragma unroll
        for (int kh = 0; kh < 2; kh++) {
            const int xk = ((quad + 4 * kh) ^ (l15 & 7)) * 8;
            s16x8 a[4], b[4];
#pragma unroll
            for (int mi = 0; mi < 4; mi++)
                a[mi] = *(const s16x8*)(lb + (wr * 64 + mi * 16 + l15) * 64 + xk);
#pragma unroll
            for (int ni = 0; ni < 4; ni++)
                b[ni] = *(const s16x8*)(lb + 8192 + (wc * 64 + ni * 16 + l15) * 64 + xk);
#pragma unroll
            for (int mi = 0; mi < 4; mi++)
#pragma unroll
                for (int ni = 0; ni < 4; ni++)
                    acc[mi][ni] = __builtin_amdgcn_mfma_f32_16x16x32_bf16(
                        a[mi], b[ni], acc[mi][ni], 0, 0, 0);
        }

        __builtin_amdgcn_sched_barrier(0);   // reads/MFMAs can't sink below
        asm volatile("s_waitcnt lgkmcnt(0)" ::: "memory");  // reads retired
        __builtin_amdgcn_s_barrier();
        __builtin_amdgcn_sched_barrier(0);   // STAGE can't hoist above
        if (t + 2 < nt) STAGE(t + 2, t & 1);
    }
#undef STAGE

#pragma unroll
    for (int mi = 0; mi < 4; mi++) {
#pragma unroll
        for (int i = 0; i < 4; i++) {
            const int r = tileRow + wr * 64 + mi * 16 + quad * 4 + i;
            const bool rok = (r < M);
#pragma unroll
            for (int ni = 0; ni < 4; ni++) {
                const int c = tileCol + wc * 64 + ni * 16 + l15;
                float v = acc[mi][ni][i] + bias[c];
                if (MODE == 2) {
                    if (tileCol < 256) {     // attention_bond half -> per-head sums
                        float s = v;
                        s += __shfl_xor(s, 1, 16);
                        s += __shfl_xor(s, 2, 16);
                        s += __shfl_xor(s, 4, 16);
                        s += __shfl_xor(s, 8, 16);
                        if (rok && l15 == 0) atomicAdd(&absum[r * 8 + (c >> 5)], s);
                    } else {                 // value_bond half
                        if (rok) Cb[(size_t)r * 256 + (c - 256)] = f2bf(v);
                    }
                } else if (MODE == 3) {
                    if (rok) Cf[(size_t)r * N + c] = v;
                } else if (MODE == 4) {
                    if (rok) {
                        Cf[(size_t)r * N + c] = v;
                        C2b[(size_t)r * N + c] = f2bf(v);
                    }
                } else {  // MODE 5: fused qkv
                    const int which = c >> 9;
                    const int cc = c & 511;
                    if (which == 1 && cc >= 256)
                        v += auxemb[(size_t)auxidx[min(r, M - 1)] * 256 + (cc - 256)];
                    if (rok) Cb[((size_t)which * M + r) * 512 + cc] = f2bf(v);
                }
            }
        }
    }
}

// ---------------------------------------------------------------------------
// DIAGNOSTIC (one arm, this round only): loads-only clone of gemm128<3>'s
// staging path — identical geometry, fences, vmcnt schedule, XCD swizzle,
// INCLUDING the A2b row-gather. No ds_read/MFMA. K-sequence repeated 4x so
// this dispatch is the top-5 max under either hypothesis (direct readout).
// Keep-alive stores go to Cf (= bondp), fully overwritten by the real
// gemm128<3> afterwards -> outputs bitwise unchanged.
// Readout: T_staging = dur/4.  >=75us -> staging-bound (branch A);
// <=35us -> compute/epilogue (branch B); else mixed (branch C).
// ---------------------------------------------------------------------------
template <int V>
__global__ __launch_bounds__(256) void gemm_abl(
    const u16* __restrict__ Abf, const u16* __restrict__ A2b,
    const u16* __restrict__ BT, float* __restrict__ Cf,
    const int* __restrict__ auxidx, int M, int K)
{
    __shared__ u16 lsmem[2 * 16384];
    const int tid = threadIdx.x;

    const int gx = gridDim.x;
    const int nwg = gx * gridDim.y;
    int flat = blockIdx.y * gx + blockIdx.x;
    {
        const int q = nwg >> 3, r8 = nwg & 7;
        const int xcd = flat & 7, loc = flat >> 3;
        flat = (xcd < r8 ? xcd * (q + 1) : r8 * (q + 1) + (xcd - r8) * q) + loc;
    }
    const int tileRow = (flat / gx) * 128;
    const int tileCol = (flat % gx) * 128;

    const int srow = tid >> 3;
    const int ks = ((tid & 7) ^ (srow & 7)) * 8;

    const u16 *gA[4], *gB[4], *gA2[4];
#pragma unroll
    for (int j = 0; j < 4; j++) {
        const int ra = j * 32 + srow;
        gA[j] = Abf + (size_t)(tileRow + ra) * 256 + ks;
        gB[j] = BT + (size_t)(tileCol + ra) * K + ks;
        gA2[j] = A2b + (size_t)auxidx[min(tileRow + ra, M - 1)] * 256 + ks;
    }

#define STAGEA(TK, BUF)                                                        \
    {                                                                          \
        u16* lb_ = lsmem + (BUF)*16384;                                        \
        const int kk_ = (TK)*64;                                               \
        _Pragma("unroll")                                                      \
        for (int j = 0; j < 4; j++) {                                          \
            const u16* sa = (kk_ < 256) ? gA[j] + kk_ : gA2[j] + (kk_ - 256);  \
            gll16(sa, lb_ + j * 2048 + tid * 8);                               \
            gll16(gB[j] + kk_, lb_ + 8192 + j * 2048 + tid * 8);               \
        }                                                                      \
    }

    const int nt = K >> 6;
    for (int rep = 0; rep < 4; ++rep) {
        STAGEA(0, 0);
        STAGEA(1, 1);
        for (int t = 0; t < nt; ++t) {
            if (t + 2 < nt) asm volatile("s_waitcnt vmcnt(8)" ::: "memory");
            else            asm volatile("s_waitcnt vmcnt(0)" ::: "memory");
            __builtin_amdgcn_s_barrier();
            __builtin_amdgcn_sched_barrier(0);
            // (loads-only: the ds_read+MFMA phase is intentionally absent)
            __builtin_amdgcn_sched_barrier(0);
            asm volatile("s_waitcnt lgkmcnt(0)" ::: "memory");
            __builtin_amdgcn_s_barrier();
            __builtin_amdgcn_sched_barrier(0);
            if (t + 2 < nt) STAGEA(t + 2, t & 1);
        }
    }
#undef STAGEA

    asm volatile("s_waitcnt vmcnt(0) lgkmcnt(0)" ::: "memory");
    float kv = *(const float*)(lsmem + (size_t)tid * 8);   // consume LDS
    Cf[(size_t)(blockIdx.y * gridDim.x + blockIdx.x) * 256 + tid] = kv;  // scratch
}

// ---------------- consolidated prep: 6 weight transposes + qkv bias concat
// ---------------- + dist_emb per-head row sums, in ONE launch -------------
__global__ __launch_bounds__(256) void prep_k(
    const float* __restrict__ Wq_w, const float* __restrict__ Wk_w,
    const float* __restrict__ Wv_w, const float* __restrict__ be_w,
    const float* __restrict__ out_w, const float* __restrict__ bu_w,
    u16* __restrict__ wT,
    const float* __restrict__ Wq_b, const float* __restrict__ Wk_b,
    const float* __restrict__ Wv_b, float* __restrict__ biasC,
    const float* __restrict__ dist_emb, float* __restrict__ distsum)
{
    const int b = blockIdx.x;
    if (b < 3072) {   // 6 transposes, 512 blocks each (131072 elems)
        const int idx6 = b >> 9;
        const int r = ((b & 511) << 8) + threadIdx.x;
        const float* s = (idx6 == 0) ? Wq_w : (idx6 == 1) ? Wk_w
                       : (idx6 == 2) ? Wv_w : (idx6 == 3) ? be_w
                       : (idx6 == 4) ? out_w : bu_w;
        u16* dst = wT + (size_t)idx6 * 131072;
        if (idx6 < 4) {   // 256 x 512 -> BT[512][256]
            const int n = r >> 8, k = r & 255;
            dst[r] = f2bf(s[(size_t)k * 512 + n]);
        } else {          // 512 x 256 -> BT[256][512]
            const int n = r >> 9, k = r & 511;
            dst[r] = f2bf(s[(size_t)k * 256 + n]);
        }
    } else {
        const int u = (b - 3072) * 256 + threadIdx.x;
        if (u < 512) biasC[u] = Wq_b[u];
        else if (u < 1024) biasC[u] = Wk_b[u - 512];
        else if (u < 1536) biasC[u] = Wv_b[u - 1024];
        else if (u < 1536 + 520) {
            const float* p = dist_emb + (size_t)(u - 1536) * 32;
            float sm = 0.f;
#pragma unroll
            for (int j = 0; j < 32; j++) sm += p[j];
            distsum[u - 1536] = sm;
        }
    }
}

// fp32 -> bf16 for f_node AND f_bond (padded rows zeroed), one launch
__global__ __launch_bounds__(256) void cvt2_k(
    const float* __restrict__ f_node, const float* __restrict__ f_bond,
    u16* __restrict__ fnb, u16* __restrict__ fbb,
    int N_, int MPN, int EB, int MPB)
{
    const int t = blockIdx.x * 256 + threadIdx.x;
    const int q1 = MPN * 64;   // quads of f_node part (256 cols / 4)
    const int q2 = MPB * 64;
    if (t < q1) {
        const int r = t >> 6;
        f32x4 v = {0.f, 0.f, 0.f, 0.f};
        if (r < N_) v = *(const f32x4*)(f_node + (size_t)t * 4);
        u16x4 o;
#pragma unroll
        for (int j = 0; j < 4; j++) o[j] = f2bf(v[j]);
        *(u16x4*)(fnb + (size_t)t * 4) = o;
    } else if (t < q1 + q2) {
        const int u = t - q1;
        const int r = u >> 6;
        f32x4 v = {0.f, 0.f, 0.f, 0.f};
        if (r < EB) v = *(const f32x4*)(f_bond + (size_t)u * 4);
        u16x4 o;
#pragma unroll
        for (int j = 0; j < 4; j++) o[j] = f2bf(v[j]);
        *(u16x4*)(fbb + (size_t)u * 4) = o;
    }
}

// -------------------- CSR build (both graphs fused) ------------------------
__global__ __launch_bounds__(256) void hist2_k(const int* __restrict__ bdst,
                                               const int* __restrict__ qidx,
                                               int* __restrict__ cnt,  // [2*N]
                                               int N_, int EL, int EG)
{
    const int e = blockIdx.x * 256 + threadIdx.x;
    if (e < EL) atomicAdd(&cnt[bdst[e]], 1);
    else if (e < EL + EG) atomicAdd(&cnt[N_ + qidx[e - EL]], 1);
}

// gridDim.x = 2: block 0 scans local, block 1 scans global
__global__ __launch_bounds__(1024) void scan2_k(
    const int* __restrict__ cnt_l, int* __restrict__ offs_l, int* __restrict__ cur_l,
    const int* __restrict__ cnt_g, int* __restrict__ offs_g, int* __restrict__ cur_g,
    int n)
{
    const int* cnt = blockIdx.x ? cnt_g : cnt_l;
    int* offs = blockIdx.x ? offs_g : offs_l;
    int* cursor = blockIdx.x ? cur_g : cur_l;
    __shared__ int part[1024];
    const int tid = threadIdx.x;
    const int per = (n + 1023) / 1024;   // <= 32
    int local[32];
    int s = 0;
    for (int j = 0; j < per; j++) {
        int idx = tid * per + j;
        int c = (idx < n) ? cnt[idx] : 0;
        local[j] = s;
        s += c;
    }
    part[tid] = s;
    __syncthreads();
    for (int st = 1; st < 1024; st <<= 1) {
        int v = (tid >= st) ? part[tid - st] : 0;
        __syncthreads();
        part[tid] += v;
        __syncthreads();
    }
    int pre = (tid == 0) ? 0 : part[tid - 1];
    for (int j = 0; j < per; j++) {
        int idx = tid * per + j;
        if (idx < n) { int o = pre + local[j]; offs[idx] = o; cursor[idx] = o; }
    }
    if (tid == 1023) offs[n] = part[1023];
}

__global__ __launch_bounds__(256) void scatter2_k(
    const int* __restrict__ bdst, const int* __restrict__ qidx,
    int* __restrict__ cur_l, int* __restrict__ cur_g,
    int* __restrict__ list_l, int* __restrict__ list_g, int EL, int EG)
{
    const int e = blockIdx.x * 256 + threadIdx.x;
    if (e < EL) {
        int pos = atomicAdd(&cur_l[bdst[e]], 1);
        list_l[pos] = e;
    } else if (e < EL + EG) {
        const int e2 = e - EL;
        int pos = atomicAdd(&cur_g[qidx[e2]], 1);
        list_g[pos] = e2;
    }
}

// ---------------------------------------------------------------------------
// Fused attention gather v3 (unchanged): one wave per (node, graph-half),
// chunked index prefetch via __shfl, depth-2 ping-pong row loads.
// ---------------------------------------------------------------------------
template <bool GLOB>
__device__ __forceinline__ void attn_half(
    const u16* __restrict__ qb, const u16* __restrict__ kb,
    const u16* __restrict__ vbuf, const u16* __restrict__ vb,
    const int* __restrict__ offs, const int* __restrict__ lst,
    const int* __restrict__ oth, const int* __restrict__ dist,
    const float* __restrict__ absum, const float* __restrict__ distsum,
    u16* __restrict__ out, int node, int EB, float scale)
{
    const int lane = threadIdx.x & 63;
    const int head = lane >> 3;
    const int cbase = (GLOB ? 256 : 0) + lane * 4;

    const u16x4 qv = *(const u16x4*)(qb + (size_t)node * 512 + cbase);
    const float q0 = bf2f(qv[0]), q1 = bf2f(qv[1]), q2 = bf2f(qv[2]), q3 = bf2f(qv[3]);

    const int s0 = offs[node], s1 = offs[node + 1];
    float a0 = 0.f, a1 = 0.f, a2 = 0.f, a3 = 0.f, den = 0.f;
    const u16x4 zv = {0, 0, 0, 0};

#define LOADS(S, IDX)                                                          \
    {                                                                          \
        e##S = __shfl(e_l, (IDX));                                             \
        const int src = __shfl(src_l, (IDX));                                  \
        kv##S = *(const u16x4*)(kb + (size_t)src * 512 + cbase);               \
        vv##S = *(const u16x4*)(vbuf + (size_t)src * 512 + cbase);             \
        ab##S = (e##S < EB) ? absum[e##S * 8 + head] : 0.f;                    \
        if (GLOB) {                                                            \
            const int d = __shfl(d_l, (IDX));                                  \
            ds##S = distsum[d * 8 + head];                                     \
        }                                                                      \
        if (!GLOB)                                                             \
            wv##S = (e##S < EB) ? *(const u16x4*)(vb + (size_t)e##S * 256 +    \
                                                  lane * 4)                    \
                                : zv;                                          \
    }

#define COMP(S)                                                                \
    {                                                                          \
        float t = q0 * bf2f(kv##S[0]) + q1 * bf2f(kv##S[1]) +                  \
                  q2 * bf2f(kv##S[2]) + q3 * bf2f(kv##S[3]);                   \
        t += __shfl_xor(t, 1);                                                 \
        t += __shfl_xor(t, 2);                                                 \
        t += __shfl_xor(t, 4);                                                 \
        t += ab##S;                                                            \
        if (GLOB) t += ds##S;                                                  \
        const float p = __expf(t * scale);                                     \
        den += p;                                                              \
        float v0 = bf2f(vv##S[0]), v1 = bf2f(vv##S[1]);                        \
        float v2 = bf2f(vv##S[2]), v3 = bf2f(vv##S[3]);                        \
        if (!GLOB) {                                                           \
            v0 += bf2f(wv##S[0]); v1 += bf2f(wv##S[1]);                        \
            v2 += bf2f(wv##S[2]); v3 += bf2f(wv##S[3]);                        \
        }                                                                      \
        a0 += p * v0; a1 += p * v1; a2 += p * v2; a3 += p * v3;                \
    }

    for (int base = s0; base < s1; base += 64) {
        const int cnt = min(64, s1 - base);
        const int gi = base + lane;
        int e_l = 0, src_l = 0, d_l = 0;
        if (gi < s1) {
            e_l = lst[gi];
            src_l = oth[e_l];
            if (GLOB) d_l = dist[e_l];
        }

        int eX, eY;
        u16x4 kvX, vvX, wvX = zv, kvY, vvY, wvY = zv;
        float abX, dsX = 0.f, abY, dsY = 0.f;

        LOADS(X, 0);
        int i = 0;
        for (; i + 2 <= cnt; i += 2) {
            LOADS(Y, i + 1);
            COMP(X);
            if (i + 2 < cnt) LOADS(X, i + 2);
            COMP(Y);
        }
        if (i < cnt) COMP(X);
    }
#undef LOADS
#undef COMP

    const float inv = (den > 0.f) ? 1.f / den : 0.f;   // empty segment -> 0
    u16x4 o;
    o[0] = f2bf(a0 * inv); o[1] = f2bf(a1 * inv);
    o[2] = f2bf(a2 * inv); o[3] = f2bf(a3 * inv);
    *(u16x4*)(out + (size_t)node * 512 + cbase) = o;
}

__global__ __launch_bounds__(256) void attn_fused(
    const u16* __restrict__ qb, const u16* __restrict__ kb,
    const u16* __restrict__ vbuf, const u16* __restrict__ vb,
    const int* __restrict__ offs_l, const int* __restrict__ list_l,
    const int* __restrict__ bsrc,
    const int* __restrict__ offs_g, const int* __restrict__ list_g,
    const int* __restrict__ kidx,
    const int* __restrict__ dist, const float* __restrict__ absum,
    const float* __restrict__ distsum, u16* __restrict__ out,
    int Nn, int EB, float scale)
{
    const int w = blockIdx.x * 4 + (threadIdx.x >> 6);
    if (w >= 2 * Nn) return;
    if (w < Nn)
        attn_half<false>(qb, kb, vbuf, vb, offs_l, list_l, bsrc, dist, absum,
                         distsum, out, w, EB, scale);
    else
        attn_half<true>(qb, kb, vbuf, vb, offs_g, list_g, kidx, dist, absum,
                        distsum, out, w - Nn, EB, scale);
}

extern "C" void kernel_launch(void* const* d_in, const int* in_sizes, int n_in,
                              void* d_out, int out_size, void* d_ws, size_t ws_size,
                              hipStream_t stream)
{
    // ---- inputs fp32 / int32; OUTPUTS fp32 ----
    const float* f_node  = (const float*)d_in[0];
    const float* f_bond  = (const float*)d_in[1];
    const int* deg       = (const int*)d_in[2];
    const int* dist      = (const int*)d_in[3];
    const int* bond_idx  = (const int*)d_in[4];
    const int* qidx      = (const int*)d_in[5];
    const int* kidx      = (const int*)d_in[6];
    // d_in[7]: attention_bond_idx == arange(E_BOND) (relied upon)
    const float* deg_emb = (const float*)d_in[8];
    const float* dist_emb= (const float*)d_in[9];
    const float* Wq_w = (const float*)d_in[10]; const float* Wq_b = (const float*)d_in[11];
    const float* Wk_w = (const float*)d_in[12]; const float* Wk_b = (const float*)d_in[13];
    const float* Wv_w = (const float*)d_in[14]; const float* Wv_b = (const float*)d_in[15];
    const float* out_w = (const float*)d_in[16]; const float* out_b = (const float*)d_in[17];
    const float* be_w  = (const float*)d_in[18]; const float* be_b  = (const float*)d_in[19];
    const float* bu_w  = (const float*)d_in[20]; const float* bu_b  = (const float*)d_in[21];

    const int N_ = in_sizes[0] / 256;   // 20000
    const int EB = in_sizes[1] / 256;   // 60000
    const int EL = in_sizes[4] / 2;     // 80000
    const int EG = in_sizes[5];         // 400000
    const float scale = 0.17677669529663689f;  // 1/sqrt(32)

    const int MPN = ((N_ + 127) / 128) * 128;   // 20096
    const int MPB = ((EB + 127) / 128) * 128;   // 60032

    const int* bsrc = bond_idx;
    const int* bdst = bond_idx + EL;

    // ---- workspace (~160 MB) ----
    u16* qb   = (u16*)d_ws;                      // N x 512 bf16   } contiguous
    u16* kb   = qb + (size_t)N_ * 512;           // N x 512        } for MODE 5
    u16* vbuf = kb + (size_t)N_ * 512;           // N x 512        } flat store
    u16* vb   = vbuf + (size_t)N_ * 512;         // EB x 256 (value_bond)
    u16* wT   = vb + (size_t)EB * 256;           // 6 x 131072 bf16
    u16* wqT = wT;                               // wq|wk|wv contiguous = MODE5 B
    u16* beT = wT + 3 * 131072;
    u16* owT = wT + 4 * 131072;
    u16* buT = wT + 5 * 131072;
    float* distsum  = (float*)(wT + 6 * 131072); // 520 (pad 1024)
    float* biasC    = distsum + 1024;            // 1536 concat qkv bias
    u16* attn_out = (u16*)(biasC + 1536);        // MPN x 512 bf16 (pad rows unused)
    u16* fnb      = attn_out;                    // alias: f_node bf16 MPN x 256 (dead after qkv)
    u16* fbb      = attn_out + (size_t)MPN * 512;// f_bond bf16 MPB x 256
    u16* outb     = fbb + (size_t)MPB * 256;     // N x 256 bf16 shadow of out
    float* absum    = (float*)(outb + (size_t)N_ * 256); // EB*8 } zeroed
    int*   cnt_l    = (int*)(absum + (size_t)EB * 8);    // N   } zeroed
    int*   cnt_g    = cnt_l + N_;                        // N   } zeroed
    size_t zbytes   = ((size_t)EB * 8 + 2 * (size_t)N_) * 4;
    int*   offs_l   = cnt_g + N_;                // N+1 (pad 4)
    int*   offs_g   = offs_l + N_ + 4;           // N+1 (pad 4)
    int*   cur_l    = offs_g + N_ + 4;           // N
    int*   cur_g    = cur_l + N_;                // N
    int*   list_l   = cur_g + N_;                // EL
    int*   list_g   = list_l + EL;               // EG

    float* outp  = (float*)d_out;                // N x 256 fp32
    float* bondp = outp + (size_t)N_ * 256;      // EB x 256 fp32

    hipMemsetAsync((void*)absum, 0, zbytes, stream);

    // consolidated prep: 6 transposes + bias concat + distsum (one launch)
    prep_k<<<3072 + 9, 256, 0, stream>>>(Wq_w, Wk_w, Wv_w, be_w, out_w, bu_w,
                                         wT, Wq_b, Wk_b, Wv_b, biasC,
                                         dist_emb, distsum);

    // fp32 -> bf16 A conversions (one launch)
    cvt2_k<<<(MPN * 64 + MPB * 64 + 255) / 256, 256, 0, stream>>>(
        f_node, f_bond, fnb, fbb, N_, MPN, EB, MPB);

    // CSR build: fused hist / 2-block scan / fused scatter
    hist2_k<<<(EL + EG + 255) / 256, 256, 0, stream>>>(bdst, qidx, cnt_l, N_, EL, EG);
    scan2_k<<<2, 1024, 0, stream>>>(cnt_l, offs_l, cur_l, cnt_g, offs_g, cur_g, N_);
    scatter2_k<<<(EL + EG + 255) / 256, 256, 0, stream>>>(bdst, qidx, cur_l, cur_g,
                                                          list_l, list_g, EL, EG);

    // fused QKV GEMM (M=N_, Ncols=1536, K=256)
    dim3 g5(12, MPN / 128);
    gemm128<5><<<g5, 256, 0, stream>>>(fnb, nullptr, wqT, biasC, qb, nullptr, nullptr, deg_emb, deg, nullptr, N_, 1536, 256);

    // bond GEMM (M=EB, N=512, K=256): attn half -> absum, value half -> vb
    dim3 gb(4, MPB / 128);
    gemm128<2><<<gb, 256, 0, stream>>>(fbb, nullptr, beT, be_b, vb, nullptr, nullptr, nullptr, nullptr, absum, EB, 512, 256);

    // fused attention (one wave per node-half, all 8 heads; no atomics) -> bf16
    attn_fused<<<(2 * N_ + 3) / 4, 256, 0, stream>>>(qb, kb, vbuf, vb,
        offs_l, list_l, bsrc, offs_g, list_g, kidx, dist, absum, distsum,
        attn_out, N_, EB, scale);

    // out = attn_out @ out_w + out_b  (M=N_, N=256, K=512) -> fp32 d_out + bf16 shadow
    dim3 go(2, MPN / 128);
    gemm128<4><<<go, 256, 0, stream>>>(attn_out, nullptr, owT, out_b, nullptr, outp, outb, nullptr, nullptr, nullptr, N_, 256, 512);

    // DIAGNOSTIC dispatch (this round only): loads-only x4 on MODE-3's shape.
    // Writes scratch into bondp, which the real gemm128<3> fully overwrites.
    dim3 gu(2, MPB / 128);
    gemm_abl<1><<<gu, 256, 0, stream>>>(fbb, outb, buT, bondp, bsrc, EB, 512);

    // bond_out = [f_bond | out[src]] @ bond_update_w + b (M=EB, N=256, K=512)
    gemm128<3><<<gu, 256, 0, stream>>>(fbb, outb, buT, bu_b, nullptr, bondp, nullptr, nullptr, bsrc, nullptr, EB, 256, 512);
}

// Round 10
// 525.068 us; speedup vs baseline: 1.1014x; 1.1014x over previous
//
#include <hip/hip_runtime.h>
#include <math.h>

typedef unsigned short u16;
typedef unsigned int u32;
typedef __attribute__((ext_vector_type(8))) short s16x8;
typedef __attribute__((ext_vector_type(4))) unsigned short u16x4;
typedef __attribute__((ext_vector_type(4))) float f32x4;

__device__ __forceinline__ float bf2f(u16 x) { return __uint_as_float(((u32)x) << 16); }
__device__ __forceinline__ u16 f2bf(float f) {
    u32 u = __float_as_uint(f);
    u32 r = u + 0x7fffu + ((u >> 16) & 1u);   // RNE
    return (u16)(r >> 16);
}

// async global->LDS, 16 B per lane (LDS dest = wave-uniform base + lane*16).
__device__ __forceinline__ void gll16(const u16* g, u16* l) {
    __builtin_amdgcn_global_load_lds((const __attribute__((address_space(1))) void*)g,
                                     (__attribute__((address_space(3))) void*)l,
                                     16, 0, 0);
}

// ---------------------------------------------------------------------------
// GEMM v5: HIGH-OCCUPANCY clean pipeline. 128x128 tile, BK=32, 4 waves,
// 2 LDS buffers of 16 KB each (32 KB total -> 5 blocks/CU, ~20 waves/CU).
// r9 ablation: loads-only = ~10us vs full 91us -> staging path is NOT the
// wall; compute phase is latency-exposed. r2-r7 matrix: every clean-pipeline
// variant ran at 1-2 blocks/CU; the untested cell is clean pipeline + high
// occupancy (TLP fills the latency per m114). This kernel fills that cell.
// Staging/read XOR swizzle maps are r3's (HW-refcheck'd); fence protocol is
// r6's (HW-refcheck'd):
//   vmcnt(N) ; s_barrier ; SCHED0 ; [ds_read+MFMA] ; SCHED0 ; lgkmcnt(0) ;
//   s_barrier ; SCHED0 ; STAGE(t+2)
// Counted vmcnt(4): stage(t+1)'s 4 loads stay in flight across the wait.
// MODE 2: tileCol<256 -> 16-lane-reduced atomicAdd absum[r*8+c/32];
//         tileCol>=256 -> bf16 Cb at pitch 256 (value_bond)
// MODE 3: A-concat: k<256 from Abf[r] (pitch 256), k>=256 from A2b[auxidx[r]]
//         (pitch 256, row gather); fp32 C store
// MODE 4: fp32 C store + bf16 shadow C2b store
// MODE 5: fused QKV: BT concat [wq|wk|wv] (1536 x 256), bias concat 1536;
//         c>>9 selects q/k/v output; k-half cols>=256 add deg_emb[deg[r]].
// ---------------------------------------------------------------------------
template <int MODE>
__global__ __launch_bounds__(256) void gemm128(
    const u16* __restrict__ Abf, const u16* __restrict__ A2b,
    const u16* __restrict__ BT, const float* __restrict__ bias,
    u16* __restrict__ Cb, float* __restrict__ Cf, u16* __restrict__ C2b,
    const float* __restrict__ auxemb, const int* __restrict__ auxidx,
    float* __restrict__ absum, int M, int N, int K)
{
    __shared__ u16 lsmem[2 * 8192];   // 2 buf x (A 4096 u16 | B 4096 u16) = 32 KB

    const int tid = threadIdx.x;
    const int wave = tid >> 6;
    const int lane = tid & 63;
    const int l15 = lane & 15;
    const int quad = lane >> 4;
    const int wr = wave >> 1, wc = wave & 1;

    // XCD-bijective swizzle (m204): contiguous flat-id chunk per XCD.
    const int gx = gridDim.x;
    const int nwg = gx * gridDim.y;
    int flat = blockIdx.y * gx + blockIdx.x;
    {
        const int q = nwg >> 3, r8 = nwg & 7;
        const int xcd = flat & 7, loc = flat >> 3;
        flat = (xcd < r8 ? xcd * (q + 1) : r8 * (q + 1) + (xcd - r8) * q) + loc;
    }
    const int tileRow = (flat / gx) * 128;
    const int tileCol = (flat % gx) * 128;

    // r3 staging map (HW-refcheck'd): thread t covers row t>>2 (A0/B0) and
    // row 64+(t>>2) (A1/B1); source k-chunk (t&3)^((t>>3)&3) -> linear LDS
    // dest tid*16B (global_load_lds can't scatter; swizzle the SOURCE).
    const int srow = tid >> 2;
    const int sk8 = (((tid & 3) ^ ((tid >> 3) & 3)) * 8);   // u16 off in [0,32)

    const u16 *gA0, *gA1, *gA0b = nullptr, *gA1b = nullptr;
    if (MODE == 3) {
        gA0 = Abf + (size_t)(tileRow + srow) * 256 + sk8;
        gA1 = Abf + (size_t)(tileRow + 64 + srow) * 256 + sk8;
        gA0b = A2b + (size_t)auxidx[min(tileRow + srow, M - 1)] * 256 + sk8;
        gA1b = A2b + (size_t)auxidx[min(tileRow + 64 + srow, M - 1)] * 256 + sk8;
    } else {
        gA0 = Abf + (size_t)(tileRow + srow) * K + sk8;
        gA1 = Abf + (size_t)(tileRow + 64 + srow) * K + sk8;
    }
    const u16* gB0 = BT + (size_t)(tileCol + srow) * K + sk8;
    const u16* gB1 = BT + (size_t)(tileCol + 64 + srow) * K + sk8;

    const int lofs = tid * 8;   // linear per-thread LDS offset (u16 units)

#define STAGE(TK, BUF)                                                         \
    {                                                                          \
        u16* lb_ = lsmem + (BUF)*8192;                                         \
        const int kk_ = (TK)*32;                                               \
        if (MODE == 3) {                                                       \
            const u16* a0 = (kk_ < 256) ? gA0 + kk_ : gA0b + (kk_ - 256);      \
            const u16* a1 = (kk_ < 256) ? gA1 + kk_ : gA1b + (kk_ - 256);      \
            gll16(a0, lb_ + lofs);                                             \
            gll16(a1, lb_ + 2048 + lofs);                                      \
        } else {                                                               \
            gll16(gA0 + kk_, lb_ + lofs);                                      \
            gll16(gA1 + kk_, lb_ + 2048 + lofs);                               \
        }                                                                      \
        gll16(gB0 + kk_, lb_ + 4096 + lofs);                                   \
        gll16(gB1 + kk_, lb_ + 4096 + 2048 + lofs);                            \
    }

    f32x4 acc[4][4] = {};
    const int nt = K >> 5;

    STAGE(0, 0);
    STAGE(1, 1);

    // read-side swizzle (r3-verified): chunk = quad ^ ((row>>1)&3)
    const int xq8 = (quad ^ ((l15 >> 1) & 3)) * 8;
    const int aoff = (wr * 64 + l15) * 32 + xq8;        // + mi*512
    const int boff = 4096 + (wc * 64 + l15) * 32 + xq8; // + ni*512

    for (int t = 0; t < nt; ++t) {
        // own tile-t loads landed (stage t+1's 4 stay in flight); barrier:
        // ALL waves' tile-t loads landed.
        if (t + 2 < nt) asm volatile("s_waitcnt vmcnt(4)" ::: "memory");
        else            asm volatile("s_waitcnt vmcnt(0)" ::: "memory");
        __builtin_amdgcn_s_barrier();
        __builtin_amdgcn_sched_barrier(0);   // nothing hoists above barrier

        const u16* lb = lsmem + (t & 1) * 8192;
        s16x8 a[4], b[4];
#pragma unroll
        for (int mi = 0; mi < 4; mi++)
            a[mi] = *(const s16x8*)(lb + aoff + mi * 512);
#pragma unroll
        for (int ni = 0; ni < 4; ni++)
            b[ni] = *(const s16x8*)(lb + boff + ni * 512);
#pragma unroll
        for (int mi = 0; mi < 4; mi++)
#pragma unroll
            for (int ni = 0; ni < 4; ni++)
                acc[mi][ni] = __builtin_amdgcn_mfma_f32_16x16x32_bf16(
                    a[mi], b[ni], acc[mi][ni], 0, 0, 0);

        __builtin_amdgcn_sched_barrier(0);   // reads/MFMAs can't sink below
        asm volatile("s_waitcnt lgkmcnt(0)" ::: "memory");  // reads retired
        __builtin_amdgcn_s_barrier();
        __builtin_amdgcn_sched_barrier(0);   // STAGE can't hoist above
        if (t + 2 < nt) STAGE(t + 2, t & 1);
    }
#undef STAGE

#pragma unroll
    for (int mi = 0; mi < 4; mi++) {
#pragma unroll
        for (int i = 0; i < 4; i++) {
            const int r = tileRow + wr * 64 + mi * 16 + quad * 4 + i;
            const bool rok = (r < M);
#pragma unroll
            for (int ni = 0; ni < 4; ni++) {
                const int c = tileCol + wc * 64 + ni * 16 + l15;
                float v = acc[mi][ni][i] + bias[c];
                if (MODE == 2) {
                    if (tileCol < 256) {     // attention_bond half -> per-head sums
                        float s = v;
                        s += __shfl_xor(s, 1, 16);
                        s += __shfl_xor(s, 2, 16);
                        s += __shfl_xor(s, 4, 16);
                        s += __shfl_xor(s, 8, 16);
                        if (rok && l15 == 0) atomicAdd(&absum[r * 8 + (c >> 5)], s);
                    } else {                 // value_bond half
                        if (rok) Cb[(size_t)r * 256 + (c - 256)] = f2bf(v);
                    }
                } else if (MODE == 3) {
                    if (rok) Cf[(size_t)r * N + c] = v;
                } else if (MODE == 4) {
                    if (rok) {
                        Cf[(size_t)r * N + c] = v;
                        C2b[(size_t)r * N + c] = f2bf(v);
                    }
                } else {  // MODE 5: fused qkv
                    const int which = c >> 9;
                    const int cc = c & 511;
                    if (which == 1 && cc >= 256)
                        v += auxemb[(size_t)auxidx[min(r, M - 1)] * 256 + (cc - 256)];
                    if (rok) Cb[((size_t)which * M + r) * 512 + cc] = f2bf(v);
                }
            }
        }
    }
}

// ---------------- consolidated prep: 6 weight transposes + qkv bias concat
// ---------------- + dist_emb per-head row sums, in ONE launch -------------
__global__ __launch_bounds__(256) void prep_k(
    const float* __restrict__ Wq_w, const float* __restrict__ Wk_w,
    const float* __restrict__ Wv_w, const float* __restrict__ be_w,
    const float* __restrict__ out_w, const float* __restrict__ bu_w,
    u16* __restrict__ wT,
    const float* __restrict__ Wq_b, const float* __restrict__ Wk_b,
    const float* __restrict__ Wv_b, float* __restrict__ biasC,
    const float* __restrict__ dist_emb, float* __restrict__ distsum)
{
    const int b = blockIdx.x;
    if (b < 3072) {   // 6 transposes, 512 blocks each (131072 elems)
        const int idx6 = b >> 9;
        const int r = ((b & 511) << 8) + threadIdx.x;
        const float* s = (idx6 == 0) ? Wq_w : (idx6 == 1) ? Wk_w
                       : (idx6 == 2) ? Wv_w : (idx6 == 3) ? be_w
                       : (idx6 == 4) ? out_w : bu_w;
        u16* dst = wT + (size_t)idx6 * 131072;
        if (idx6 < 4) {   // 256 x 512 -> BT[512][256]
            const int n = r >> 8, k = r & 255;
            dst[r] = f2bf(s[(size_t)k * 512 + n]);
        } else {          // 512 x 256 -> BT[256][512]
            const int n = r >> 9, k = r & 511;
            dst[r] = f2bf(s[(size_t)k * 256 + n]);
        }
    } else {
        const int u = (b - 3072) * 256 + threadIdx.x;
        if (u < 512) biasC[u] = Wq_b[u];
        else if (u < 1024) biasC[u] = Wk_b[u - 512];
        else if (u < 1536) biasC[u] = Wv_b[u - 1024];
        else if (u < 1536 + 520) {
            const float* p = dist_emb + (size_t)(u - 1536) * 32;
            float sm = 0.f;
#pragma unroll
            for (int j = 0; j < 32; j++) sm += p[j];
            distsum[u - 1536] = sm;
        }
    }
}

// fp32 -> bf16 for f_node AND f_bond (padded rows zeroed), one launch
__global__ __launch_bounds__(256) void cvt2_k(
    const float* __restrict__ f_node, const float* __restrict__ f_bond,
    u16* __restrict__ fnb, u16* __restrict__ fbb,
    int N_, int MPN, int EB, int MPB)
{
    const int t = blockIdx.x * 256 + threadIdx.x;
    const int q1 = MPN * 64;   // quads of f_node part (256 cols / 4)
    const int q2 = MPB * 64;
    if (t < q1) {
        const int r = t >> 6;
        f32x4 v = {0.f, 0.f, 0.f, 0.f};
        if (r < N_) v = *(const f32x4*)(f_node + (size_t)t * 4);
        u16x4 o;
#pragma unroll
        for (int j = 0; j < 4; j++) o[j] = f2bf(v[j]);
        *(u16x4*)(fnb + (size_t)t * 4) = o;
    } else if (t < q1 + q2) {
        const int u = t - q1;
        const int r = u >> 6;
        f32x4 v = {0.f, 0.f, 0.f, 0.f};
        if (r < EB) v = *(const f32x4*)(f_bond + (size_t)u * 4);
        u16x4 o;
#pragma unroll
        for (int j = 0; j < 4; j++) o[j] = f2bf(v[j]);
        *(u16x4*)(fbb + (size_t)u * 4) = o;
    }
}

// -------------------- CSR build (both graphs fused) ------------------------
__global__ __launch_bounds__(256) void hist2_k(const int* __restrict__ bdst,
                                               const int* __restrict__ qidx,
                                               int* __restrict__ cnt,  // [2*N]
                                               int N_, int EL, int EG)
{
    const int e = blockIdx.x * 256 + threadIdx.x;
    if (e < EL) atomicAdd(&cnt[bdst[e]], 1);
    else if (e < EL + EG) atomicAdd(&cnt[N_ + qidx[e - EL]], 1);
}

// gridDim.x = 2: block 0 scans local, block 1 scans global
__global__ __launch_bounds__(1024) void scan2_k(
    const int* __restrict__ cnt_l, int* __restrict__ offs_l, int* __restrict__ cur_l,
    const int* __restrict__ cnt_g, int* __restrict__ offs_g, int* __restrict__ cur_g,
    int n)
{
    const int* cnt = blockIdx.x ? cnt_g : cnt_l;
    int* offs = blockIdx.x ? offs_g : offs_l;
    int* cursor = blockIdx.x ? cur_g : cur_l;
    __shared__ int part[1024];
    const int tid = threadIdx.x;
    const int per = (n + 1023) / 1024;   // <= 32
    int local[32];
    int s = 0;
    for (int j = 0; j < per; j++) {
        int idx = tid * per + j;
        int c = (idx < n) ? cnt[idx] : 0;
        local[j] = s;
        s += c;
    }
    part[tid] = s;
    __syncthreads();
    for (int st = 1; st < 1024; st <<= 1) {
        int v = (tid >= st) ? part[tid - st] : 0;
        __syncthreads();
        part[tid] += v;
        __syncthreads();
    }
    int pre = (tid == 0) ? 0 : part[tid - 1];
    for (int j = 0; j < per; j++) {
        int idx = tid * per + j;
        if (idx < n) { int o = pre + local[j]; offs[idx] = o; cursor[idx] = o; }
    }
    if (tid == 1023) offs[n] = part[1023];
}

__global__ __launch_bounds__(256) void scatter2_k(
    const int* __restrict__ bdst, const int* __restrict__ qidx,
    int* __restrict__ cur_l, int* __restrict__ cur_g,
    int* __restrict__ list_l, int* __restrict__ list_g, int EL, int EG)
{
    const int e = blockIdx.x * 256 + threadIdx.x;
    if (e < EL) {
        int pos = atomicAdd(&cur_l[bdst[e]], 1);
        list_l[pos] = e;
    } else if (e < EL + EG) {
        const int e2 = e - EL;
        int pos = atomicAdd(&cur_g[qidx[e2]], 1);
        list_g[pos] = e2;
    }
}

// ---------------------------------------------------------------------------
// Fused attention gather v3 (unchanged): one wave per (node, graph-half),
// chunked index prefetch via __shfl, depth-2 ping-pong row loads.
// ---------------------------------------------------------------------------
template <bool GLOB>
__device__ __forceinline__ void attn_half(
    const u16* __restrict__ qb, const u16* __restrict__ kb,
    const u16* __restrict__ vbuf, const u16* __restrict__ vb,
    const int* __restrict__ offs, const int* __restrict__ lst,
    const int* __restrict__ oth, const int* __restrict__ dist,
    const float* __restrict__ absum, const float* __restrict__ distsum,
    u16* __restrict__ out, int node, int EB, float scale)
{
    const int lane = threadIdx.x & 63;
    const int head = lane >> 3;
    const int cbase = (GLOB ? 256 : 0) + lane * 4;

    const u16x4 qv = *(const u16x4*)(qb + (size_t)node * 512 + cbase);
    const float q0 = bf2f(qv[0]), q1 = bf2f(qv[1]), q2 = bf2f(qv[2]), q3 = bf2f(qv[3]);

    const int s0 = offs[node], s1 = offs[node + 1];
    float a0 = 0.f, a1 = 0.f, a2 = 0.f, a3 = 0.f, den = 0.f;
    const u16x4 zv = {0, 0, 0, 0};

#define LOADS(S, IDX)                                                          \
    {                                                                          \
        e##S = __shfl(e_l, (IDX));                                             \
        const int src = __shfl(src_l, (IDX));                                  \
        kv##S = *(const u16x4*)(kb + (size_t)src * 512 + cbase);               \
        vv##S = *(const u16x4*)(vbuf + (size_t)src * 512 + cbase);             \
        ab##S = (e##S < EB) ? absum[e##S * 8 + head] : 0.f;                    \
        if (GLOB) {                                                            \
            const int d = __shfl(d_l, (IDX));                                  \
            ds##S = distsum[d * 8 + head];                                     \
        }                                                                      \
        if (!GLOB)                                                             \
            wv##S = (e##S < EB) ? *(const u16x4*)(vb + (size_t)e##S * 256 +    \
                                                  lane * 4)                    \
                                : zv;                                          \
    }

#define COMP(S)                                                                \
    {                                                                          \
        float t = q0 * bf2f(kv##S[0]) + q1 * bf2f(kv##S[1]) +                  \
                  q2 * bf2f(kv##S[2]) + q3 * bf2f(kv##S[3]);                   \
        t += __shfl_xor(t, 1);                                                 \
        t += __shfl_xor(t, 2);                                                 \
        t += __shfl_xor(t, 4);                                                 \
        t += ab##S;                                                            \
        if (GLOB) t += ds##S;                                                  \
        const float p = __expf(t * scale);                                     \
        den += p;                                                              \
        float v0 = bf2f(vv##S[0]), v1 = bf2f(vv##S[1]);                        \
        float v2 = bf2f(vv##S[2]), v3 = bf2f(vv##S[3]);                        \
        if (!GLOB) {                                                           \
            v0 += bf2f(wv##S[0]); v1 += bf2f(wv##S[1]);                        \
            v2 += bf2f(wv##S[2]); v3 += bf2f(wv##S[3]);                        \
        }                                                                      \
        a0 += p * v0; a1 += p * v1; a2 += p * v2; a3 += p * v3;                \
    }

    for (int base = s0; base < s1; base += 64) {
        const int cnt = min(64, s1 - base);
        const int gi = base + lane;
        int e_l = 0, src_l = 0, d_l = 0;
        if (gi < s1) {
            e_l = lst[gi];
            src_l = oth[e_l];
            if (GLOB) d_l = dist[e_l];
        }

        int eX, eY;
        u16x4 kvX, vvX, wvX = zv, kvY, vvY, wvY = zv;
        float abX, dsX = 0.f, abY, dsY = 0.f;

        LOADS(X, 0);
        int i = 0;
        for (; i + 2 <= cnt; i += 2) {
            LOADS(Y, i + 1);
            COMP(X);
            if (i + 2 < cnt) LOADS(X, i + 2);
            COMP(Y);
        }
        if (i < cnt) COMP(X);
    }
#undef LOADS
#undef COMP

    const float inv = (den > 0.f) ? 1.f / den : 0.f;   // empty segment -> 0
    u16x4 o;
    o[0] = f2bf(a0 * inv); o[1] = f2bf(a1 * inv);
    o[2] = f2bf(a2 * inv); o[3] = f2bf(a3 * inv);
    *(u16x4*)(out + (size_t)node * 512 + cbase) = o;
}

__global__ __launch_bounds__(256) void attn_fused(
    const u16* __restrict__ qb, const u16* __restrict__ kb,
    const u16* __restrict__ vbuf, const u16* __restrict__ vb,
    const int* __restrict__ offs_l, const int* __restrict__ list_l,
    const int* __restrict__ bsrc,
    const int* __restrict__ offs_g, const int* __restrict__ list_g,
    const int* __restrict__ kidx,
    const int* __restrict__ dist, const float* __restrict__ absum,
    const float* __restrict__ distsum, u16* __restrict__ out,
    int Nn, int EB, float scale)
{
    const int w = blockIdx.x * 4 + (threadIdx.x >> 6);
    if (w >= 2 * Nn) return;
    if (w < Nn)
        attn_half<false>(qb, kb, vbuf, vb, offs_l, list_l, bsrc, dist, absum,
                         distsum, out, w, EB, scale);
    else
        attn_half<true>(qb, kb, vbuf, vb, offs_g, list_g, kidx, dist, absum,
                        distsum, out, w - Nn, EB, scale);
}

extern "C" void kernel_launch(void* const* d_in, const int* in_sizes, int n_in,
                              void* d_out, int out_size, void* d_ws, size_t ws_size,
                              hipStream_t stream)
{
    // ---- inputs fp32 / int32; OUTPUTS fp32 ----
    const float* f_node  = (const float*)d_in[0];
    const float* f_bond  = (const float*)d_in[1];
    const int* deg       = (const int*)d_in[2];
    const int* dist      = (const int*)d_in[3];
    const int* bond_idx  = (const int*)d_in[4];
    const int* qidx      = (const int*)d_in[5];
    const int* kidx      = (const int*)d_in[6];
    // d_in[7]: attention_bond_idx == arange(E_BOND) (relied upon)
    const float* deg_emb = (const float*)d_in[8];
    const float* dist_emb= (const float*)d_in[9];
    const float* Wq_w = (const float*)d_in[10]; const float* Wq_b = (const float*)d_in[11];
    const float* Wk_w = (const float*)d_in[12]; const float* Wk_b = (const float*)d_in[13];
    const float* Wv_w = (const float*)d_in[14]; const float* Wv_b = (const float*)d_in[15];
    const float* out_w = (const float*)d_in[16]; const float* out_b = (const float*)d_in[17];
    const float* be_w  = (const float*)d_in[18]; const float* be_b  = (const float*)d_in[19];
    const float* bu_w  = (const float*)d_in[20]; const float* bu_b  = (const float*)d_in[21];

    const int N_ = in_sizes[0] / 256;   // 20000
    const int EB = in_sizes[1] / 256;   // 60000
    const int EL = in_sizes[4] / 2;     // 80000
    const int EG = in_sizes[5];         // 400000
    const float scale = 0.17677669529663689f;  // 1/sqrt(32)

    const int MPN = ((N_ + 127) / 128) * 128;   // 20096
    const int MPB = ((EB + 127) / 128) * 128;   // 60032

    const int* bsrc = bond_idx;
    const int* bdst = bond_idx + EL;

    // ---- workspace (~160 MB) ----
    u16* qb   = (u16*)d_ws;                      // N x 512 bf16   } contiguous
    u16* kb   = qb + (size_t)N_ * 512;           // N x 512        } for MODE 5
    u16* vbuf = kb + (size_t)N_ * 512;           // N x 512        } flat store
    u16* vb   = vbuf + (size_t)N_ * 512;         // EB x 256 (value_bond)
    u16* wT   = vb + (size_t)EB * 256;           // 6 x 131072 bf16
    u16* wqT = wT;                               // wq|wk|wv contiguous = MODE5 B
    u16* beT = wT + 3 * 131072;
    u16* owT = wT + 4 * 131072;
    u16* buT = wT + 5 * 131072;
    float* distsum  = (float*)(wT + 6 * 131072); // 520 (pad 1024)
    float* biasC    = distsum + 1024;            // 1536 concat qkv bias
    u16* attn_out = (u16*)(biasC + 1536);        // MPN x 512 bf16 (pad rows unused)
    u16* fnb      = attn_out;                    // alias: f_node bf16 MPN x 256 (dead after qkv)
    u16* fbb      = attn_out + (size_t)MPN * 512;// f_bond bf16 MPB x 256
    u16* outb     = fbb + (size_t)MPB * 256;     // N x 256 bf16 shadow of out
    float* absum    = (float*)(outb + (size_t)N_ * 256); // EB*8 } zeroed
    int*   cnt_l    = (int*)(absum + (size_t)EB * 8);    // N   } zeroed
    int*   cnt_g    = cnt_l + N_;                        // N   } zeroed
    size_t zbytes   = ((size_t)EB * 8 + 2 * (size_t)N_) * 4;
    int*   offs_l   = cnt_g + N_;                // N+1 (pad 4)
    int*   offs_g   = offs_l + N_ + 4;           // N+1 (pad 4)
    int*   cur_l    = offs_g + N_ + 4;           // N
    int*   cur_g    = cur_l + N_;                // N
    int*   list_l   = cur_g + N_;                // EL
    int*   list_g   = list_l + EL;               // EG

    float* outp  = (float*)d_out;                // N x 256 fp32
    float* bondp = outp + (size_t)N_ * 256;      // EB x 256 fp32

    hipMemsetAsync((void*)absum, 0, zbytes, stream);

    // consolidated prep: 6 transposes + bias concat + distsum (one launch)
    prep_k<<<3072 + 9, 256, 0, stream>>>(Wq_w, Wk_w, Wv_w, be_w, out_w, bu_w,
                                         wT, Wq_b, Wk_b, Wv_b, biasC,
                                         dist_emb, distsum);

    // fp32 -> bf16 A conversions (one launch)
    cvt2_k<<<(MPN * 64 + MPB * 64 + 255) / 256, 256, 0, stream>>>(
        f_node, f_bond, fnb, fbb, N_, MPN, EB, MPB);

    // CSR build: fused hist / 2-block scan / fused scatter
    hist2_k<<<(EL + EG + 255) / 256, 256, 0, stream>>>(bdst, qidx, cnt_l, N_, EL, EG);
    scan2_k<<<2, 1024, 0, stream>>>(cnt_l, offs_l, cur_l, cnt_g, offs_g, cur_g, N_);
    scatter2_k<<<(EL + EG + 255) / 256, 256, 0, stream>>>(bdst, qidx, cur_l, cur_g,
                                                          list_l, list_g, EL, EG);

    // fused QKV GEMM (M=N_, Ncols=1536, K=256)
    dim3 g5(12, MPN / 128);
    gemm128<5><<<g5, 256, 0, stream>>>(fnb, nullptr, wqT, biasC, qb, nullptr, nullptr, deg_emb, deg, nullptr, N_, 1536, 256);

    // bond GEMM (M=EB, N=512, K=256): attn half -> absum, value half -> vb
    dim3 gb(4, MPB / 128);
    gemm128<2><<<gb, 256, 0, stream>>>(fbb, nullptr, beT, be_b, vb, nullptr, nullptr, nullptr, nullptr, absum, EB, 512, 256);

    // fused attention (one wave per node-half, all 8 heads; no atomics) -> bf16
    attn_fused<<<(2 * N_ + 3) / 4, 256, 0, stream>>>(qb, kb, vbuf, vb,
        offs_l, list_l, bsrc, offs_g, list_g, kidx, dist, absum, distsum,
        attn_out, N_, EB, scale);

    // out = attn_out @ out_w + out_b  (M=N_, N=256, K=512) -> fp32 d_out + bf16 shadow
    dim3 go(2, MPN / 128);
    gemm128<4><<<go, 256, 0, stream>>>(attn_out, nullptr, owT, out_b, nullptr, outp, outb, nullptr, nullptr, nullptr, N_, 256, 512);

    // bond_out = [f_bond | out[src]] @ bond_update_w + b (M=EB, N=256, K=512)
    dim3 gu(2, MPB / 128);
    gemm128<3><<<gu, 256, 0, stream>>>(fbb, outb, buT, bu_b, nullptr, bondp, nullptr, nullptr, bsrc, nullptr, EB, 256, 512);
}